// Round 9
// baseline (221.285 us; speedup 1.0000x reference)
//
#include <hip/hip_runtime.h>
#include <hip/hip_bf16.h>
#include <stdint.h>

#define DEVFN __device__ __forceinline__

typedef __attribute__((ext_vector_type(8))) short short8;
typedef __attribute__((ext_vector_type(4))) float f32x4;
typedef __attribute__((ext_vector_type(16))) float f32x16;

constexpr int S_LEN = 2048;   // sequence length
constexpr int HDIM  = 2048;   // hidden H (= K of GEMMs)
constexpr int NHEAD = 16;
constexpr int HD    = 128;    // head dim

DEVFN unsigned short f2bf(float f){
  union { float f; unsigned u; } x; x.f = f;
  unsigned r = x.u + 0x7fffu + ((x.u >> 16) & 1u);
  return (unsigned short)(r >> 16);
}

typedef const __attribute__((address_space(1))) void* gas1_ptr;
typedef __attribute__((address_space(3))) void* las3_ptr;

DEVFN void gl_lds16(const void* g, void* l){
  __builtin_amdgcn_global_load_lds((gas1_ptr)g, (las3_ptr)l, 16, 0, 0);
}

DEVFN f32x4 mfma16(short8 a, short8 b, f32x4 c){
  return __builtin_amdgcn_mfma_f32_16x16x32_bf16(a, b, c, 0, 0, 0);
}

DEVFN f32x16 mfma32(short8 a, short8 b, f32x16 c){
  return __builtin_amdgcn_mfma_f32_32x32x16_bf16(a, b, c, 0, 0, 0);
}

DEVFN unsigned cvtpk_bf16(float lo, float hi){
  unsigned w;
  asm("v_cvt_pk_bf16_f32 %0, %1, %2" : "=v"(w) : "v"(lo), "v"(hi));
  return w;
}

// ---------------- small prep kernels ----------------

// x f32 -> bf16, 8 elems/thread, 16B stores.
__global__ void cast_x_kernel(const float* __restrict__ in, unsigned short* __restrict__ out){
  int i = (blockIdx.x * 256 + threadIdx.x) * 8;
  float4 a = *(const float4*)(in + i);
  float4 b = *(const float4*)(in + i + 4);
  union { unsigned short s[8]; short8 v; } o;
  o.s[0] = f2bf(a.x); o.s[1] = f2bf(a.y); o.s[2] = f2bf(a.z); o.s[3] = f2bf(a.w);
  o.s[4] = f2bf(b.x); o.s[5] = f2bf(b.y); o.s[6] = f2bf(b.z); o.s[7] = f2bf(b.w);
  *(short8*)(out + i) = o.v;
}

// f32 [K][N] -> bf16 [N][K] for all 4 weights (z = which weight).
// 64x64 tiles; float2 reads (256B/32-lane), short8 writes (128B row segments).
__global__ void transpose_cast_w4(const float* __restrict__ w0, const float* __restrict__ w1,
                                  const float* __restrict__ w2, const float* __restrict__ w3,
                                  unsigned short* __restrict__ out){
  __shared__ float tile[64][65];
  const int tid = threadIdx.x;
  const int kb = blockIdx.x * 64, nb = blockIdx.y * 64, z = blockIdx.z;
  const float* in = (z == 0) ? w0 : (z == 1) ? w1 : (z == 2) ? w2 : w3;
  unsigned short* op = out + (size_t)z * HDIM * HDIM;

  const int rr = tid >> 5;            // 0..7
  const int cc = (tid & 31) * 2;      // 0..62
  #pragma unroll
  for (int i = 0; i < 8; i++){
    int r = i*8 + rr;                 // k-local
    float2 v = *(const float2*)(in + (size_t)(kb + r) * HDIM + nb + cc);
    tile[r][cc]   = v.x;
    tile[r][cc+1] = v.y;
  }
  __syncthreads();
  #pragma unroll
  for (int p = 0; p < 2; p++){
    int task = p*256 + tid;
    int n_l = task >> 3;              // 0..63
    int k8  = (task & 7) * 8;         // 0..56
    union { unsigned short s[8]; short8 v; } o;
    #pragma unroll
    for (int j = 0; j < 8; j++)
      o.s[j] = f2bf(tile[k8 + j][n_l]);
    *(short8*)(op + (size_t)(nb + n_l) * HDIM + kb + k8) = o.v;
  }
}

// ---------------- GEMM core: A[M][K] x Bt[N][K] -> acc (128x128 tile) ----------------
// 256 threads = 4 waves (2x2), per-wave 64x64 = 4x4 fragments of 16x16.

DEVFN void gemm_core_bt(const unsigned short* __restrict__ A,
                        const unsigned short* __restrict__ Bt,
                        int K, int m0, int n0, char* ls, f32x4 (&acc)[4][4]){
  const int t = threadIdx.x;
  const int wid = t >> 6, lane = t & 63;
  const int wr = wid >> 1, wc = wid & 1;
  const int l15 = lane & 15, lg = lane >> 4;
  char* lsA = ls;
  char* lsB = ls + 16384;

  for (int k0 = 0; k0 < K; k0 += 64){
    __syncthreads();
    #pragma unroll
    for (int i = 0; i < 4; i++){
      int o = (t + i*256) * 16;
      int row = o >> 7;
      int col = (o & 127) ^ ((row & 7) << 4);
      gl_lds16((const char*)A + ((size_t)(m0 + row) * K + k0) * 2 + col, lsA + o);
    }
    #pragma unroll
    for (int i = 0; i < 4; i++){
      int o = (t + i*256) * 16;
      int row = o >> 7;
      int col = (o & 127) ^ ((row & 7) << 4);
      gl_lds16((const char*)Bt + ((size_t)(n0 + row) * K + k0) * 2 + col, lsB + o);
    }
    __syncthreads();
    #pragma unroll
    for (int kk = 0; kk < 2; kk++){
      short8 af[4], bfr[4];
      #pragma unroll
      for (int i = 0; i < 4; i++){
        int ra = wr*64 + i*16 + l15;
        af[i]  = *(const short8*)(lsA + ra*128 + ((kk*64 + lg*16) ^ ((ra & 7) << 4)));
        int rb = wc*64 + i*16 + l15;
        bfr[i] = *(const short8*)(lsB + rb*128 + ((kk*64 + lg*16) ^ ((rb & 7) << 4)));
      }
      #pragma unroll
      for (int i = 0; i < 4; i++)
        #pragma unroll
        for (int j = 0; j < 4; j++)
          acc[i][j] = mfma16(af[i], bfr[j], acc[i][j]);
    }
  }
}

// QKV projection: xb[4096][2048] x Wt[6144][2048].
// Q (scaled by 1/sqrt(HD)*log2e) and K scatter to (b,h,s,d); V is written
// TRANSPOSED to Vt (b,h,d,s) via an LDS 128x128 transpose.
__global__ __launch_bounds__(256, 4)
void gemm_qkv(const unsigned short* __restrict__ xb, const unsigned short* __restrict__ Wt,
              unsigned short* __restrict__ Qb, unsigned short* __restrict__ Kb,
              unsigned short* __restrict__ Vt){
  __shared__ __align__(16) char ls[32768];
  f32x4 acc[4][4];
  const f32x4 z4 = {0.f, 0.f, 0.f, 0.f};
  #pragma unroll
  for (int i = 0; i < 4; i++)
    #pragma unroll
    for (int j = 0; j < 4; j++) acc[i][j] = z4;

  const int m0 = blockIdx.x * 128;
  const int n0 = blockIdx.y * 128;
  gemm_core_bt(xb, Wt, HDIM, m0, n0, ls, acc);

  const float qscale = 0.08838834764831845f * 1.4426950408889634f;
  const int t = threadIdx.x, wid = t >> 6, lane = t & 63;
  const int wr = wid >> 1, wc = wid & 1, l15 = lane & 15, lg = lane >> 4;
  const int bb = m0 >> 11, ss0 = m0 & 2047;

  if (n0 < 4096){
    unsigned short* base = (n0 < 2048) ? Qb : Kb;
    const float sc = (n0 < 2048) ? qscale : 1.0f;
    #pragma unroll
    for (int j = 0; j < 4; j++){
      int n = n0 + wc*64 + j*16 + l15;
      int hh = (n >> 7) & 15, d = n & 127;
      #pragma unroll
      for (int i = 0; i < 4; i++){
        #pragma unroll
        for (int r = 0; r < 4; r++){
          int ss = ss0 + wr*64 + i*16 + lg*4 + r;
          base[(((size_t)bb * NHEAD + hh) * S_LEN + ss) * HD + d] = f2bf(acc[i][j][r] * sc);
        }
      }
    }
  } else {
    // V: LDS transpose -> coalesced (b,h,d,s) store
    const int hh = (n0 - 4096) >> 7;
    __syncthreads();
    #pragma unroll
    for (int j = 0; j < 4; j++){
      int nn = wc*64 + j*16 + l15;        // d
      #pragma unroll
      for (int i = 0; i < 4; i++){
        int mmb = (wr*64 + i*16 + lg*4) * 2;
        unsigned w0 = cvtpk_bf16(acc[i][j][0], acc[i][j][1]);
        unsigned w1 = cvtpk_bf16(acc[i][j][2], acc[i][j][3]);
        *(unsigned*)(ls + nn*256 + ((mmb    ) ^ ((nn & 7) << 4))) = w0;
        *(unsigned*)(ls + nn*256 + ((mmb + 4) ^ ((nn & 7) << 4))) = w1;
      }
    }
    __syncthreads();
    unsigned short* vout = Vt + (((size_t)bb * NHEAD + hh) * HD) * S_LEN;
    #pragma unroll
    for (int p = 0; p < 8; p++){
      int idx = p*256 + t;
      int d = idx >> 4;
      int m8 = (idx & 15) * 8;
      short8 v = *(const short8*)(ls + d*256 + ((m8*2) ^ ((d & 7) << 4)));
      *(short8*)(vout + (size_t)d * S_LEN + ss0 + m8) = v;
    }
  }
}

// Output projection: Ob[4096][2048] x Wot[2048][2048] -> out f32 [4096][2048]
__global__ __launch_bounds__(256, 4)
void gemm_out(const unsigned short* __restrict__ Ob, const unsigned short* __restrict__ Wot,
              float* __restrict__ out){
  __shared__ __align__(16) char ls[32768];
  f32x4 acc[4][4];
  const f32x4 z4 = {0.f, 0.f, 0.f, 0.f};
  #pragma unroll
  for (int i = 0; i < 4; i++)
    #pragma unroll
    for (int j = 0; j < 4; j++) acc[i][j] = z4;

  const int m0 = blockIdx.x * 128;
  const int n0 = blockIdx.y * 128;
  gemm_core_bt(Ob, Wot, HDIM, m0, n0, ls, acc);

  const int t = threadIdx.x, wid = t >> 6, lane = t & 63;
  const int wr = wid >> 1, wc = wid & 1, l15 = lane & 15, lg = lane >> 4;
  #pragma unroll
  for (int i = 0; i < 4; i++){
    #pragma unroll
    for (int r = 0; r < 4; r++){
      int m = m0 + wr*64 + i*16 + lg*4 + r;
      #pragma unroll
      for (int j = 0; j < 4; j++){
        int n = n0 + wc*64 + j*16 + l15;
        out[(size_t)m * HDIM + n] = acc[i][j][r];
      }
    }
  }
}

// ---------------- causal flash attention: swapped 32x32 MFMA + lagged-PV pipeline --
// grid = 512 linear blocks, 256 threads (4 waves x QBLK=32 rows).
// bh = L&31 (XCD locality), qt = z<8 ? z : 23-z (pair balance).
// Loop body t: stage(t+1) -> QK(t) -> PV(t-1) [lagged, V 3-buffered] -> SM(t).
// Counted drain vmcnt(4): V(t+1) loads stay in flight across the barrier (they
// are only consumed by PV in body t+2); last two bodies drain to 0 so the
// post-loop PV and epilogue see complete data.
__global__ __launch_bounds__(256, 2)
void attn_kernel(const unsigned short* __restrict__ Q,
                 const unsigned short* __restrict__ Kg,
                 const unsigned short* __restrict__ Vt,
                 unsigned short* __restrict__ Ob){
  __shared__ __align__(16) unsigned short Kl[2][64*128];   // 2 x 16 KB, rows 256B, xor (row&15)<<4
  __shared__ __align__(16) unsigned short Vl[3][128*64];   // 3 x 16 KB, rows 128B, xor (row&7)<<4

  const int t = threadIdx.x;
  const int wid = t >> 6, lane = t & 63;
  const int l31 = lane & 31, hi = lane >> 5;
  const int L = blockIdx.x;
  const int bh = L & 31;
  const int z = L >> 5;
  const int qt = (z < 8) ? z : 23 - z;
  const int b = bh >> 4, h = bh & 15;
  const unsigned short* Qp = Q  + (size_t)bh * S_LEN * HD;
  const unsigned short* Kp = Kg + (size_t)bh * S_LEN * HD;
  const unsigned short* Vp = Vt + (size_t)bh * S_LEN * HD; // (d, s)
  const int q0 = qt * 128;
  const int wrow0 = q0 + wid * 32;
  const int qrow = wrow0 + l31;
  const int nt = 2 * qt + 2;              // block k-tiles (always even)
  const int ntw = (wrow0 >> 6) + 1;       // tiles this wave computes

  auto stage = [&](int tdx){
    char* kb = (char*)&Kl[tdx & 1][0];
    char* vb = (char*)&Vl[tdx % 3][0];
    const int k0 = tdx * 64;
    #pragma unroll
    for (int i = 0; i < 4; i++){ // K tile: 64 rows x 256 B (issued first -> older)
      int o = (t + i*256) * 16;
      int row = o >> 8;
      int col = (o & 255) ^ ((row & 15) << 4);
      gl_lds16((const char*)(Kp + (size_t)(k0 + row) * HD) + col, kb + o);
    }
    #pragma unroll
    for (int i = 0; i < 4; i++){ // V tile: 128 d-rows x 128 B (issued last -> newest 4)
      int o = (t + i*256) * 16;
      int row = o >> 7;
      int col = (o & 127) ^ ((row & 7) << 4);
      gl_lds16((const char*)(Vp + (size_t)row * S_LEN + k0) + col, vb + o);
    }
  };

  short8 qf[8];
  #pragma unroll
  for (int dk = 0; dk < 8; dk++)
    qf[dk] = *(const short8*)(Qp + (size_t)qrow * HD + dk*16 + hi*8);

  f32x16 oacc[4];
  #pragma unroll
  for (int db = 0; db < 4; db++)
    #pragma unroll
    for (int r = 0; r < 16; r++) oacc[db][r] = 0.f;
  float mrun = -1e30f, lsum = 0.f;
  short8 paA[4], paB[4];

  auto do_pv = [&](short8 (&pprev)[4], const char* vb){
    __builtin_amdgcn_s_setprio(1);
    #pragma unroll
    for (int ks = 0; ks < 4; ks++){
      #pragma unroll
      for (int db = 0; db < 4; db++){
        int vr = db*32 + l31;
        short8 vf = *(const short8*)(vb + vr*128 + ((ks*32 + hi*16) ^ ((vr & 7) << 4)));
        oacc[db] = mfma32(vf, pprev[ks], oacc[db]);
      }
    }
    __builtin_amdgcn_s_setprio(0);
  };

  auto body = [&](int tdx, short8 (&pcur)[4], short8 (&pprev)[4]){
    if (tdx + 1 < nt) stage(tdx + 1);
    const char* Kb_ = (const char*)&Kl[tdx & 1][0];
    const bool doQK = (tdx < ntw);
    const bool doPV = (tdx >= 1) && (tdx <= ntw);

    f32x16 sacc[2];
    if (doQK){
      #pragma unroll
      for (int cb = 0; cb < 2; cb++)
        #pragma unroll
        for (int r = 0; r < 16; r++) sacc[cb][r] = 0.f;
      __builtin_amdgcn_s_setprio(1);
      #pragma unroll
      for (int dk = 0; dk < 8; dk++){
        #pragma unroll
        for (int cb = 0; cb < 2; cb++){
          int kr = cb*32 + l31;
          short8 af = *(const short8*)(Kb_ + kr*256 + ((dk*32 + hi*16) ^ ((kr & 15) << 4)));
          sacc[cb] = mfma32(af, qf[dk], sacc[cb]);
        }
      }
      __builtin_amdgcn_s_setprio(0);
    }

    if (doPV) do_pv(pprev, (const char*)&Vl[(tdx - 1) % 3][0]);

    if (doQK){
      const int k0 = tdx * 64;
      if (tdx == ntw - 1){
        #pragma unroll
        for (int cb = 0; cb < 2; cb++)
          #pragma unroll
          for (int r = 0; r < 16; r++){
            int kcol = k0 + cb*32 + (r & 3) + 8*(r >> 2) + 4*hi;
            if (kcol > qrow) sacc[cb][r] = -1e30f;
          }
      }
      float mv[8];
      #pragma unroll
      for (int i = 0; i < 8; i++)
        mv[i] = fmaxf(fmaxf(sacc[0][i], sacc[0][i+8]), fmaxf(sacc[1][i], sacc[1][i+8]));
      #pragma unroll
      for (int s = 4; s > 0; s >>= 1)
        #pragma unroll
        for (int i = 0; i < 4; i++)
          if (i < s) mv[i] = fmaxf(mv[i], mv[i+s]);
      float mx = fmaxf(mv[0], __shfl_xor(mv[0], 32, 64));
      if (!__all(mx <= mrun + 8.f)){
        float mnew = fmaxf(mrun, mx);
        float alpha = exp2f(mrun - mnew);
        mrun = mnew;
        lsum *= alpha;
        #pragma unroll
        for (int db = 0; db < 4; db++)
          #pragma unroll
          for (int r = 0; r < 16; r++) oacc[db][r] *= alpha;
      }
      float ls = 0.f;
      #pragma unroll
      for (int cb = 0; cb < 2; cb++)
        #pragma unroll
        for (int r = 0; r < 16; r++){
          float p = exp2f(sacc[cb][r] - mrun);
          sacc[cb][r] = p;
          ls += p;
        }
      lsum += ls;
      #pragma unroll
      for (int ks = 0; ks < 4; ks++){
        int cb = ks >> 1, bs = (ks & 1) * 8;
        unsigned B1 = cvtpk_bf16(sacc[cb][bs+0], sacc[cb][bs+1]);
        unsigned B2 = cvtpk_bf16(sacc[cb][bs+2], sacc[cb][bs+3]);
        unsigned A1 = cvtpk_bf16(sacc[cb][bs+4], sacc[cb][bs+5]);
        unsigned A2 = cvtpk_bf16(sacc[cb][bs+6], sacc[cb][bs+7]);
        asm("v_permlane32_swap_b32 %0, %1" : "+v"(B1), "+v"(A1));
        asm("v_permlane32_swap_b32 %0, %1" : "+v"(B2), "+v"(A2));
        union { unsigned u[4]; short8 v; } pk;
        pk.u[0] = B1; pk.u[1] = B2; pk.u[2] = A1; pk.u[3] = A2;
        pcur[ks] = pk.v;
      }
    }

    // counted drain (T4): V(t+1)'s 4 loads (newest) may stay in flight; they are
    // consumed only in body t+2. Last two bodies drain fully for the epilogue.
    if (tdx + 2 < nt) asm volatile("s_waitcnt vmcnt(4)" ::: "memory");
    else              asm volatile("s_waitcnt vmcnt(0)" ::: "memory");
    __builtin_amdgcn_s_barrier();
  };

  stage(0);
  asm volatile("s_waitcnt vmcnt(0)" ::: "memory");
  __builtin_amdgcn_s_barrier();

  #pragma unroll 1
  for (int tt = 0; tt < nt; tt += 2){
    body(tt,     paA, paB);
    body(tt + 1, paB, paA);
  }
  if (ntw == nt) do_pv(paB, (const char*)&Vl[(nt - 1) % 3][0]);

  float lt = lsum + __shfl_xor(lsum, 32, 64);
  float inv = 1.f / lt;
  #pragma unroll
  for (int db = 0; db < 4; db++)
    #pragma unroll
    for (int r = 0; r < 16; r++) oacc[db][r] *= inv;

  __builtin_amdgcn_s_barrier();
  char* reg_lds = (char*)&Kl[0][0] + wid * 8192;
  #pragma unroll
  for (int ms = 0; ms < 8; ms++){
    int db = ms >> 1, bs = (ms & 1) * 8;
    unsigned B1 = cvtpk_bf16(oacc[db][bs+0], oacc[db][bs+1]);
    unsigned B2 = cvtpk_bf16(oacc[db][bs+2], oacc[db][bs+3]);
    unsigned A1 = cvtpk_bf16(oacc[db][bs+4], oacc[db][bs+5]);
    unsigned A2 = cvtpk_bf16(oacc[db][bs+6], oacc[db][bs+7]);
    asm("v_permlane32_swap_b32 %0, %1" : "+v"(B1), "+v"(A1));
    asm("v_permlane32_swap_b32 %0, %1" : "+v"(B2), "+v"(A2));
    union { unsigned u[4]; short8 v; } pk;
    pk.u[0] = B1; pk.u[1] = B2; pk.u[2] = A1; pk.u[3] = A2;
    int byteo = l31*256 + ((ms*32 + hi*16) ^ ((l31 & 7) << 4));
    *(short8*)(reg_lds + byteo) = pk.v;
  }
  #pragma unroll
  for (int i = 0; i < 8; i++){
    int r = (lane >> 4) + i*4;
    int c = lane & 15;
    short8 v = *(const short8*)(reg_lds + r*256 + ((c*16) ^ ((r & 7) << 4)));
    *(short8*)(Ob + ((size_t)(b * S_LEN + wrow0 + r)) * 2048 + h*128 + c*8) = v;
  }
}

// ---------------- launcher ----------------
// ws layout (bytes):
//   [0,          16777216)  xb   (4096x2048 bf16)      -- reused as Ob after QKV GEMM
//   [16777216,   41943040)  Wt   (6144x2048 bf16)
//   [41943040,   50331648)  Wot  (2048x2048 bf16)
//   [50331648,   67108864)  Qb   (b,h,s,d bf16)
//   [67108864,   83886080)  Kb
//   [83886080,  100663296)  Vt   (b,h,d,s bf16, written directly by gemm_qkv)
extern "C" void kernel_launch(void* const* d_in, const int* in_sizes, int n_in,
                              void* d_out, int out_size, void* d_ws, size_t ws_size,
                              hipStream_t stream){
  const float* x  = (const float*)d_in[0];
  // d_in[1] = mask (causal tril; hardcoded in attn_kernel)
  const float* Wq = (const float*)d_in[2];
  const float* Wk = (const float*)d_in[3];
  const float* Wv = (const float*)d_in[4];
  const float* Wo = (const float*)d_in[5];

  char* ws = (char*)d_ws;
  unsigned short* xb  = (unsigned short*)(ws);
  unsigned short* Wt  = (unsigned short*)(ws + 16777216);
  unsigned short* Wot = (unsigned short*)(ws + 41943040);
  unsigned short* Qb  = (unsigned short*)(ws + 50331648);
  unsigned short* Kb  = (unsigned short*)(ws + 67108864);
  unsigned short* Vt  = (unsigned short*)(ws + 83886080);
  unsigned short* Ob  = xb;  // alias: xb dead after gemm_qkv

  cast_x_kernel<<<4096, 256, 0, stream>>>(x, xb);
  transpose_cast_w4<<<dim3(32, 32, 4), 256, 0, stream>>>(Wq, Wk, Wv, Wo, Wt);

  gemm_qkv<<<dim3(32, 48), 256, 0, stream>>>(xb, Wt, Qb, Kb, Vt);

  attn_kernel<<<512, 256, 0, stream>>>(Qb, Kb, Vt, Ob);

  gemm_out<<<dim3(32, 16), 256, 0, stream>>>(Ob, Wot, (float*)d_out);
}

// Round 12
// 218.509 us; speedup vs baseline: 1.0127x; 1.0127x over previous
//
#include <hip/hip_runtime.h>
#include <hip/hip_bf16.h>
#include <stdint.h>

#define DEVFN __device__ __forceinline__

typedef __attribute__((ext_vector_type(8))) short short8;
typedef __attribute__((ext_vector_type(4))) float f32x4;
typedef __attribute__((ext_vector_type(16))) float f32x16;

constexpr int S_LEN = 2048;   // sequence length
constexpr int HDIM  = 2048;   // hidden H (= K of GEMMs)
constexpr int NHEAD = 16;
constexpr int HD    = 128;    // head dim

DEVFN unsigned short f2bf(float f){
  union { float f; unsigned u; } x; x.f = f;
  unsigned r = x.u + 0x7fffu + ((x.u >> 16) & 1u);
  return (unsigned short)(r >> 16);
}

typedef const __attribute__((address_space(1))) void* gas1_ptr;
typedef __attribute__((address_space(3))) void* las3_ptr;

DEVFN void gl_lds16(const void* g, void* l){
  __builtin_amdgcn_global_load_lds((gas1_ptr)g, (las3_ptr)l, 16, 0, 0);
}

DEVFN f32x4 mfma16(short8 a, short8 b, f32x4 c){
  return __builtin_amdgcn_mfma_f32_16x16x32_bf16(a, b, c, 0, 0, 0);
}

DEVFN f32x16 mfma32(short8 a, short8 b, f32x16 c){
  return __builtin_amdgcn_mfma_f32_32x32x16_bf16(a, b, c, 0, 0, 0);
}

DEVFN unsigned cvtpk_bf16(float lo, float hi){
  unsigned w;
  asm("v_cvt_pk_bf16_f32 %0, %1, %2" : "=v"(w) : "v"(lo), "v"(hi));
  return w;
}

// ---------------- small prep kernels ----------------

// x f32 -> bf16, 8 elems/thread, 16B stores.
__global__ void cast_x_kernel(const float* __restrict__ in, unsigned short* __restrict__ out){
  int i = (blockIdx.x * 256 + threadIdx.x) * 8;
  float4 a = *(const float4*)(in + i);
  float4 b = *(const float4*)(in + i + 4);
  union { unsigned short s[8]; short8 v; } o;
  o.s[0] = f2bf(a.x); o.s[1] = f2bf(a.y); o.s[2] = f2bf(a.z); o.s[3] = f2bf(a.w);
  o.s[4] = f2bf(b.x); o.s[5] = f2bf(b.y); o.s[6] = f2bf(b.z); o.s[7] = f2bf(b.w);
  *(short8*)(out + i) = o.v;
}

// f32 [K][N] -> bf16 [N][K] for all 4 weights (z = which weight).
// 64x64 tiles; float2 reads (256B/32-lane), short8 writes (128B row segments).
__global__ void transpose_cast_w4(const float* __restrict__ w0, const float* __restrict__ w1,
                                  const float* __restrict__ w2, const float* __restrict__ w3,
                                  unsigned short* __restrict__ out){
  __shared__ float tile[64][65];
  const int tid = threadIdx.x;
  const int kb = blockIdx.x * 64, nb = blockIdx.y * 64, z = blockIdx.z;
  const float* in = (z == 0) ? w0 : (z == 1) ? w1 : (z == 2) ? w2 : w3;
  unsigned short* op = out + (size_t)z * HDIM * HDIM;

  const int rr = tid >> 5;            // 0..7
  const int cc = (tid & 31) * 2;      // 0..62
  #pragma unroll
  for (int i = 0; i < 8; i++){
    int r = i*8 + rr;                 // k-local
    float2 v = *(const float2*)(in + (size_t)(kb + r) * HDIM + nb + cc);
    tile[r][cc]   = v.x;
    tile[r][cc+1] = v.y;
  }
  __syncthreads();
  #pragma unroll
  for (int p = 0; p < 2; p++){
    int task = p*256 + tid;
    int n_l = task >> 3;              // 0..63
    int k8  = (task & 7) * 8;         // 0..56
    union { unsigned short s[8]; short8 v; } o;
    #pragma unroll
    for (int j = 0; j < 8; j++)
      o.s[j] = f2bf(tile[k8 + j][n_l]);
    *(short8*)(op + (size_t)(nb + n_l) * HDIM + kb + k8) = o.v;
  }
}

// ---------------- GEMM core: A[M][K] x Bt[N][K] -> acc (128x128 tile) ----------------
// 256 threads = 4 waves (2x2), per-wave 64x64 = 4x4 fragments of 16x16.

DEVFN void gemm_core_bt(const unsigned short* __restrict__ A,
                        const unsigned short* __restrict__ Bt,
                        int K, int m0, int n0, char* ls, f32x4 (&acc)[4][4]){
  const int t = threadIdx.x;
  const int wid = t >> 6, lane = t & 63;
  const int wr = wid >> 1, wc = wid & 1;
  const int l15 = lane & 15, lg = lane >> 4;
  char* lsA = ls;
  char* lsB = ls + 16384;

  for (int k0 = 0; k0 < K; k0 += 64){
    __syncthreads();
    #pragma unroll
    for (int i = 0; i < 4; i++){
      int o = (t + i*256) * 16;
      int row = o >> 7;
      int col = (o & 127) ^ ((row & 7) << 4);
      gl_lds16((const char*)A + ((size_t)(m0 + row) * K + k0) * 2 + col, lsA + o);
    }
    #pragma unroll
    for (int i = 0; i < 4; i++){
      int o = (t + i*256) * 16;
      int row = o >> 7;
      int col = (o & 127) ^ ((row & 7) << 4);
      gl_lds16((const char*)Bt + ((size_t)(n0 + row) * K + k0) * 2 + col, lsB + o);
    }
    __syncthreads();
    #pragma unroll
    for (int kk = 0; kk < 2; kk++){
      short8 af[4], bfr[4];
      #pragma unroll
      for (int i = 0; i < 4; i++){
        int ra = wr*64 + i*16 + l15;
        af[i]  = *(const short8*)(lsA + ra*128 + ((kk*64 + lg*16) ^ ((ra & 7) << 4)));
        int rb = wc*64 + i*16 + l15;
        bfr[i] = *(const short8*)(lsB + rb*128 + ((kk*64 + lg*16) ^ ((rb & 7) << 4)));
      }
      #pragma unroll
      for (int i = 0; i < 4; i++)
        #pragma unroll
        for (int j = 0; j < 4; j++)
          acc[i][j] = mfma16(af[i], bfr[j], acc[i][j]);
    }
  }
}

// QKV projection: xb[4096][2048] x Wt[6144][2048].
// Q (scaled by 1/sqrt(HD)*log2e) and K scatter to (b,h,s,d); V is written
// TRANSPOSED to Vt (b,h,d,s) via an LDS 128x128 transpose.
__global__ __launch_bounds__(256, 4)
void gemm_qkv(const unsigned short* __restrict__ xb, const unsigned short* __restrict__ Wt,
              unsigned short* __restrict__ Qb, unsigned short* __restrict__ Kb,
              unsigned short* __restrict__ Vt){
  __shared__ __align__(16) char ls[32768];
  f32x4 acc[4][4];
  const f32x4 z4 = {0.f, 0.f, 0.f, 0.f};
  #pragma unroll
  for (int i = 0; i < 4; i++)
    #pragma unroll
    for (int j = 0; j < 4; j++) acc[i][j] = z4;

  const int m0 = blockIdx.x * 128;
  const int n0 = blockIdx.y * 128;
  gemm_core_bt(xb, Wt, HDIM, m0, n0, ls, acc);

  const float qscale = 0.08838834764831845f * 1.4426950408889634f;
  const int t = threadIdx.x, wid = t >> 6, lane = t & 63;
  const int wr = wid >> 1, wc = wid & 1, l15 = lane & 15, lg = lane >> 4;
  const int bb = m0 >> 11, ss0 = m0 & 2047;

  if (n0 < 4096){
    unsigned short* base = (n0 < 2048) ? Qb : Kb;
    const float sc = (n0 < 2048) ? qscale : 1.0f;
    #pragma unroll
    for (int j = 0; j < 4; j++){
      int n = n0 + wc*64 + j*16 + l15;
      int hh = (n >> 7) & 15, d = n & 127;
      #pragma unroll
      for (int i = 0; i < 4; i++){
        #pragma unroll
        for (int r = 0; r < 4; r++){
          int ss = ss0 + wr*64 + i*16 + lg*4 + r;
          base[(((size_t)bb * NHEAD + hh) * S_LEN + ss) * HD + d] = f2bf(acc[i][j][r] * sc);
        }
      }
    }
  } else {
    // V: LDS transpose -> coalesced (b,h,d,s) store
    const int hh = (n0 - 4096) >> 7;
    __syncthreads();
    #pragma unroll
    for (int j = 0; j < 4; j++){
      int nn = wc*64 + j*16 + l15;        // d
      #pragma unroll
      for (int i = 0; i < 4; i++){
        int mmb = (wr*64 + i*16 + lg*4) * 2;
        unsigned w0 = cvtpk_bf16(acc[i][j][0], acc[i][j][1]);
        unsigned w1 = cvtpk_bf16(acc[i][j][2], acc[i][j][3]);
        *(unsigned*)(ls + nn*256 + ((mmb    ) ^ ((nn & 7) << 4))) = w0;
        *(unsigned*)(ls + nn*256 + ((mmb + 4) ^ ((nn & 7) << 4))) = w1;
      }
    }
    __syncthreads();
    unsigned short* vout = Vt + (((size_t)bb * NHEAD + hh) * HD) * S_LEN;
    #pragma unroll
    for (int p = 0; p < 8; p++){
      int idx = p*256 + t;
      int d = idx >> 4;
      int m8 = (idx & 15) * 8;
      short8 v = *(const short8*)(ls + d*256 + ((m8*2) ^ ((d & 7) << 4)));
      *(short8*)(vout + (size_t)d * S_LEN + ss0 + m8) = v;
    }
  }
}

// Output projection: Ob[4096][2048] x Wot[2048][2048] -> out f32 [4096][2048]
__global__ __launch_bounds__(256, 4)
void gemm_out(const unsigned short* __restrict__ Ob, const unsigned short* __restrict__ Wot,
              float* __restrict__ out){
  __shared__ __align__(16) char ls[32768];
  f32x4 acc[4][4];
  const f32x4 z4 = {0.f, 0.f, 0.f, 0.f};
  #pragma unroll
  for (int i = 0; i < 4; i++)
    #pragma unroll
    for (int j = 0; j < 4; j++) acc[i][j] = z4;

  const int m0 = blockIdx.x * 128;
  const int n0 = blockIdx.y * 128;
  gemm_core_bt(Ob, Wot, HDIM, m0, n0, ls, acc);

  const int t = threadIdx.x, wid = t >> 6, lane = t & 63;
  const int wr = wid >> 1, wc = wid & 1, l15 = lane & 15, lg = lane >> 4;
  #pragma unroll
  for (int i = 0; i < 4; i++){
    #pragma unroll
    for (int r = 0; r < 4; r++){
      int m = m0 + wr*64 + i*16 + lg*4 + r;
      #pragma unroll
      for (int j = 0; j < 4; j++){
        int n = n0 + wc*64 + j*16 + l15;
        out[(size_t)m * HDIM + n] = acc[i][j][r];
      }
    }
  }
}

// -------- causal flash attention: paired q-supertiles, shared staging --------
// grid = 256 blocks x 512 threads (8 waves). Block (bh = L&31, p = L>>5, p in 0..7):
// waves 0-3 -> q-tile p (rows p*128 + wq*32), waves 4-7 -> q-tile 15-p.
// Short group's k-range is a PREFIX of the long group's -> one shared K/V
// staging stream (K dbuf x2, V x3 for lagged PV; 80 KB LDS, explicit layout).
// Waves wid and wid+4 share a SIMD -> every SIMD gets one short + one long
// wave: per-SIMD work ~= 34 wave-tiles, uniform chip-wide. Same-bh blocks
// share an XCD (L%8 = bh%8) -> K/V L2-resident.
// Sync: full __syncthreads() per body (R6 semantics; counted drains measured
// flat in R9 and are issue-order-fragile with global_load_lds).
__global__ __launch_bounds__(512, 1)
void attn_kernel(const unsigned short* __restrict__ Q,
                 const unsigned short* __restrict__ Kg,
                 const unsigned short* __restrict__ Vt,
                 unsigned short* __restrict__ Ob){
  // explicit LDS layout: K buffers [0, 32768), V buffers [32768, 81920)
  __shared__ __align__(16) char LSD[81920];
  char* const KlB = LSD;
  char* const VlB = LSD + 32768;

  const int t = threadIdx.x;
  const int wid = t >> 6, lane = t & 63;
  const int l31 = lane & 31, hi = lane >> 5;
  const int L = blockIdx.x;
  const int bh = L & 31;
  const int p = L >> 5;                   // 0..7
  const int g = wid >> 2, wq = wid & 3;   // group, wave-in-group
  const int qt = g ? (15 - p) : p;
  const int b = bh >> 4, h = bh & 15;
  const unsigned short* Qp = Q  + (size_t)bh * S_LEN * HD;
  const unsigned short* Kp = Kg + (size_t)bh * S_LEN * HD;
  const unsigned short* Vp = Vt + (size_t)bh * S_LEN * HD; // (d, s)
  const int wrow0 = qt * 128 + wq * 32;
  const int qrow = wrow0 + l31;
  const int nt = 2 * (15 - p) + 2;        // k-tiles staged (long group's range; even)
  const int ntw = (wrow0 >> 6) + 1;       // tiles this wave computes

  auto stage = [&](int tdx){
    char* kb = KlB + (tdx & 1) * 16384;
    char* vb = VlB + (tdx % 3) * 16384;
    const int k0 = tdx * 64;
    #pragma unroll
    for (int i = 0; i < 2; i++){ // K tile: 64 rows x 256 B
      int o = (t + i*512) * 16;
      int row = o >> 8;
      int col = (o & 255) ^ ((row & 15) << 4);
      gl_lds16((const char*)(Kp + (size_t)(k0 + row) * HD) + col, kb + o);
    }
    #pragma unroll
    for (int i = 0; i < 2; i++){ // V tile: 128 d-rows x 128 B
      int o = (t + i*512) * 16;
      int row = o >> 7;
      int col = (o & 127) ^ ((row & 7) << 4);
      gl_lds16((const char*)(Vp + (size_t)row * S_LEN + k0) + col, vb + o);
    }
  };

  short8 qf[8];
  #pragma unroll
  for (int dk = 0; dk < 8; dk++)
    qf[dk] = *(const short8*)(Qp + (size_t)qrow * HD + dk*16 + hi*8);

  f32x16 oacc[4];
  #pragma unroll
  for (int db = 0; db < 4; db++)
    #pragma unroll
    for (int r = 0; r < 16; r++) oacc[db][r] = 0.f;
  float mrun = -1e30f, lsum = 0.f;
  short8 paA[4], paB[4];

  auto do_pv = [&](short8 (&pprev)[4], const char* vb){
    __builtin_amdgcn_s_setprio(1);
    #pragma unroll
    for (int ks = 0; ks < 4; ks++){
      #pragma unroll
      for (int db = 0; db < 4; db++){
        int vr = db*32 + l31;
        short8 vf = *(const short8*)(vb + vr*128 + ((ks*32 + hi*16) ^ ((vr & 7) << 4)));
        oacc[db] = mfma32(vf, pprev[ks], oacc[db]);
      }
    }
    __builtin_amdgcn_s_setprio(0);
  };

  auto body = [&](int tdx, short8 (&pcur)[4], short8 (&pprev)[4]){
    if (tdx + 1 < nt) stage(tdx + 1);
    const char* Kb_ = KlB + (tdx & 1) * 16384;
    const bool doQK = (tdx < ntw);
    const bool doPV = (tdx >= 1) && (tdx <= ntw);

    f32x16 sacc[2];
    if (doQK){
      #pragma unroll
      for (int cb = 0; cb < 2; cb++)
        #pragma unroll
        for (int r = 0; r < 16; r++) sacc[cb][r] = 0.f;
      __builtin_amdgcn_s_setprio(1);
      #pragma unroll
      for (int dk = 0; dk < 8; dk++){
        #pragma unroll
        for (int cb = 0; cb < 2; cb++){
          int kr = cb*32 + l31;
          short8 af = *(const short8*)(Kb_ + kr*256 + ((dk*32 + hi*16) ^ ((kr & 15) << 4)));
          sacc[cb] = mfma32(af, qf[dk], sacc[cb]);
        }
      }
      __builtin_amdgcn_s_setprio(0);
    }

    if (doPV) do_pv(pprev, VlB + ((tdx - 1) % 3) * 16384);

    if (doQK){
      const int k0 = tdx * 64;
      if (tdx == ntw - 1){
        #pragma unroll
        for (int cb = 0; cb < 2; cb++)
          #pragma unroll
          for (int r = 0; r < 16; r++){
            int kcol = k0 + cb*32 + (r & 3) + 8*(r >> 2) + 4*hi;
            if (kcol > qrow) sacc[cb][r] = -1e30f;
          }
      }
      float mv[8];
      #pragma unroll
      for (int i = 0; i < 8; i++)
        mv[i] = fmaxf(fmaxf(sacc[0][i], sacc[0][i+8]), fmaxf(sacc[1][i], sacc[1][i+8]));
      #pragma unroll
      for (int s = 4; s > 0; s >>= 1)
        #pragma unroll
        for (int i = 0; i < 4; i++)
          if (i < s) mv[i] = fmaxf(mv[i], mv[i+s]);
      float mx = fmaxf(mv[0], __shfl_xor(mv[0], 32, 64));
      if (!__all(mx <= mrun + 8.f)){
        float mnew = fmaxf(mrun, mx);
        float alpha = exp2f(mrun - mnew);
        mrun = mnew;
        lsum *= alpha;
        #pragma unroll
        for (int db = 0; db < 4; db++)
          #pragma unroll
          for (int r = 0; r < 16; r++) oacc[db][r] *= alpha;
      }
      float ls = 0.f;
      #pragma unroll
      for (int cb = 0; cb < 2; cb++)
        #pragma unroll
        for (int r = 0; r < 16; r++){
          float pp = exp2f(sacc[cb][r] - mrun);
          sacc[cb][r] = pp;
          ls += pp;
        }
      lsum += ls;
      #pragma unroll
      for (int ks = 0; ks < 4; ks++){
        int cb = ks >> 1, bs = (ks & 1) * 8;
        unsigned B1 = cvtpk_bf16(sacc[cb][bs+0], sacc[cb][bs+1]);
        unsigned B2 = cvtpk_bf16(sacc[cb][bs+2], sacc[cb][bs+3]);
        unsigned A1 = cvtpk_bf16(sacc[cb][bs+4], sacc[cb][bs+5]);
        unsigned A2 = cvtpk_bf16(sacc[cb][bs+6], sacc[cb][bs+7]);
        asm("v_permlane32_swap_b32 %0, %1" : "+v"(B1), "+v"(A1));
        asm("v_permlane32_swap_b32 %0, %1" : "+v"(B2), "+v"(A2));
        union { unsigned u[4]; short8 v; } pk;
        pk.u[0] = B1; pk.u[1] = B2; pk.u[2] = A1; pk.u[3] = A2;
        pcur[ks] = pk.v;
      }
    }

    __syncthreads();   // full drain + barrier: next tile landed, all waves done with cur
  };

  stage(0);
  __syncthreads();

  #pragma unroll 1
  for (int tt = 0; tt < nt; tt += 2){
    body(tt,     paA, paB);
    body(tt + 1, paB, paA);
  }
  // trailing PV for waves whose last tile is the last staged tile (long wq>=2)
  if (ntw == nt) do_pv(paB, VlB + ((nt - 1) % 3) * 16384);

  float lt = lsum + __shfl_xor(lsum, 32, 64);
  float inv = 1.f / lt;
  #pragma unroll
  for (int db = 0; db < 4; db++)
    #pragma unroll
    for (int r = 0; r < 16; r++) oacc[db][r] *= inv;

  __syncthreads();   // everyone done with K/V LDS before scratch reuse
  char* reg_lds = LSD + wid * 8192;  // 8 waves x 8 KB = 64 KB (< 80 KB, in-bounds)
  #pragma unroll
  for (int ms = 0; ms < 8; ms++){
    int db = ms >> 1, bs = (ms & 1) * 8;
    unsigned B1 = cvtpk_bf16(oacc[db][bs+0], oacc[db][bs+1]);
    unsigned B2 = cvtpk_bf16(oacc[db][bs+2], oacc[db][bs+3]);
    unsigned A1 = cvtpk_bf16(oacc[db][bs+4], oacc[db][bs+5]);
    unsigned A2 = cvtpk_bf16(oacc[db][bs+6], oacc[db][bs+7]);
    asm("v_permlane32_swap_b32 %0, %1" : "+v"(B1), "+v"(A1));
    asm("v_permlane32_swap_b32 %0, %1" : "+v"(B2), "+v"(A2));
    union { unsigned u[4]; short8 v; } pk;
    pk.u[0] = B1; pk.u[1] = B2; pk.u[2] = A1; pk.u[3] = A2;
    int byteo = l31*256 + ((ms*32 + hi*16) ^ ((l31 & 7) << 4));
    *(short8*)(reg_lds + byteo) = pk.v;
  }
  #pragma unroll
  for (int i = 0; i < 8; i++){
    int r = (lane >> 4) + i*4;
    int c = lane & 15;
    short8 v = *(const short8*)(reg_lds + r*256 + ((c*16) ^ ((r & 7) << 4)));
    *(short8*)(Ob + ((size_t)(b * S_LEN + wrow0 + r)) * 2048 + h*128 + c*8) = v;
  }
}

// ---------------- launcher ----------------
// ws layout (bytes):
//   [0,          16777216)  xb   (4096x2048 bf16)      -- reused as Ob after QKV GEMM
//   [16777216,   41943040)  Wt   (6144x2048 bf16)
//   [41943040,   50331648)  Wot  (2048x2048 bf16)
//   [50331648,   67108864)  Qb   (b,h,s,d bf16)
//   [67108864,   83886080)  Kb
//   [83886080,  100663296)  Vt   (b,h,d,s bf16, written directly by gemm_qkv)
extern "C" void kernel_launch(void* const* d_in, const int* in_sizes, int n_in,
                              void* d_out, int out_size, void* d_ws, size_t ws_size,
                              hipStream_t stream){
  const float* x  = (const float*)d_in[0];
  // d_in[1] = mask (causal tril; hardcoded in attn_kernel)
  const float* Wq = (const float*)d_in[2];
  const float* Wk = (const float*)d_in[3];
  const float* Wv = (const float*)d_in[4];
  const float* Wo = (const float*)d_in[5];

  char* ws = (char*)d_ws;
  unsigned short* xb  = (unsigned short*)(ws);
  unsigned short* Wt  = (unsigned short*)(ws + 16777216);
  unsigned short* Wot = (unsigned short*)(ws + 41943040);
  unsigned short* Qb  = (unsigned short*)(ws + 50331648);
  unsigned short* Kb  = (unsigned short*)(ws + 67108864);
  unsigned short* Vt  = (unsigned short*)(ws + 83886080);
  unsigned short* Ob  = xb;  // alias: xb dead after gemm_qkv

  cast_x_kernel<<<4096, 256, 0, stream>>>(x, xb);
  transpose_cast_w4<<<dim3(32, 32, 4), 256, 0, stream>>>(Wq, Wk, Wv, Wo, Wt);

  gemm_qkv<<<dim3(32, 48), 256, 0, stream>>>(xb, Wt, Qb, Kb, Vt);

  attn_kernel<<<256, 512, 0, stream>>>(Qb, Kb, Vt, Ob);

  gemm_out<<<dim3(32, 16), 256, 0, stream>>>(Ob, Wot, (float*)d_out);
}